// Round 1
// baseline (98.530 us; speedup 1.0000x reference)
//
#include <hip/hip_runtime.h>

// Depth-4 path signature, B=128, L=128, C=12, fp32.
// One workgroup per batch. Thread t<144 owns (i,j)=(t/12,t%12) and holds
// acc4[144] (level-4 slice), s3[12], s2, s1i entirely in registers.
// Horner-factored Chen step: 1 FMA per level-4 element per increment.
// No __syncthreads in the main loop (sig1 maintained redundantly per thread).

#define NC    12
#define NPTS  128
#define OUT_PER_B 22620   // 12 + 144 + 1728 + 20736
#define BLOCK 192

__global__ __launch_bounds__(BLOCK, 1)
void sig_kernel(const float* __restrict__ path, float* __restrict__ out, int nbatch) {
    const int b = blockIdx.x;
    const int t = threadIdx.x;

    __shared__ float P[NPTS * NC];   // 6144 B: whole path for this batch

    const float* pb = path + (size_t)b * (NPTS * NC);
    for (int idx = t; idx < NPTS * NC; idx += BLOCK) P[idx] = pb[idx];
    __syncthreads();

    if (t < 144) {
        const int i = t / 12;
        const int j = t - i * 12;

        float acc4[144];
        float s3[12];
        float s2 = 0.f;
        float s1i = 0.f;
        #pragma unroll
        for (int x = 0; x < 144; ++x) acc4[x] = 0.f;
        #pragma unroll
        for (int k = 0; k < 12; ++k) s3[k] = 0.f;

        float prev[12];
        #pragma unroll
        for (int c = 0; c < 12; ++c) prev[c] = P[c];
        float prev_i = P[i];
        float prev_j = P[j];

        for (int s = 1; s < NPTS; ++s) {
            const float* row = &P[s * NC];
            float d[12];
            #pragma unroll
            for (int c = 0; c < 12; ++c) {
                float cv = row[c];
                d[c] = cv - prev[c];
                prev[c] = cv;
            }
            // runtime-indexed LDS reads for channels i and j
            float cvi = row[i]; float d_i = cvi - prev_i; prev_i = cvi;
            float cvj = row[j]; float d_j = cvj - prev_j; prev_j = cvj;

            // Horner coefficients (use OLD s1, s2, s3)
            float A4 = (s1i + 0.25f * d_i) * (1.f / 3.f);  // (s1 + d/4)/3
            float B4 = (s2 + d_j * A4) * 0.5f;             // (s2 + dj*A4)/2
            float A3 = (s1i + d_i * (1.f / 3.f)) * 0.5f;   // (s1 + d/3)/2
            float C2 = s2 + d_j * A3;                      // level-3 coef
            float C1 = s1i + 0.5f * d_i;                   // level-2 coef

            // level 4: acc4[k][l] += (s3[k] + d[k]*B4) * d[l]
            #pragma unroll
            for (int k = 0; k < 12; ++k) {
                float C3 = s3[k] + d[k] * B4;
                #pragma unroll
                for (int l = 0; l < 12; ++l)
                    acc4[k * 12 + l] += C3 * d[l];
                s3[k] += d[k] * C2;   // level-3 update (after C3 consumed old s3)
            }
            s2  += d_j * C1;          // level-2 update
            s1i += d_i;               // level-1 update
        }

        // ---- epilogue: write signature, layout [lvl1 | lvl2 | lvl3 | lvl4] ----
        float* ob = out + (size_t)b * OUT_PER_B;
        if (j == 0) ob[i] = s1i;                      // level 1 (12)
        ob[12 + t] = s2;                              // level 2 (144)
        #pragma unroll
        for (int k = 0; k < 12; ++k)                  // level 3 (1728)
            ob[156 + t * 12 + k] = s3[k];
        #pragma unroll
        for (int x = 0; x < 144; ++x)                 // level 4 (20736)
            ob[1884 + t * 144 + x] = acc4[x];
    }
}

extern "C" void kernel_launch(void* const* d_in, const int* in_sizes, int n_in,
                              void* d_out, int out_size, void* d_ws, size_t ws_size,
                              hipStream_t stream) {
    const float* path = (const float*)d_in[0];
    float* out = (float*)d_out;
    int nbatch = in_sizes[0] / (NPTS * NC);   // = 128
    sig_kernel<<<nbatch, BLOCK, 0, stream>>>(path, out, nbatch);
}

// Round 2
// 80.007 us; speedup vs baseline: 1.2315x; 1.2315x over previous
//
#include <hip/hip_runtime.h>

// Depth-4 path signature, B=128, L=128, C=12, fp32.
// Round 2: exploit that Chen's recursion has NO cross terms in the leading
// index i. Split each batch across 2 blocks (i-halves) -> 256 blocks (all
// 256 CUs). Thread owns (i,j,k) and accumulates the 12-element l-row of
// level 4 plus s3[ijk]; s2[ij], s1[i] kept redundantly per thread (1 FMA ea).
// Increments precomputed into LDS once: row-major (for l-multiplicands, read
// as 3x float4 broadcast) and transposed (d_i/d_j/d_k as one float4 / 4 steps).
// 864 active threads = 14 waves/CU -> 3.5 waves/SIMD latency hiding.
// No barriers in the 128-step main loop.

#define NC    12
#define NPTS  128
#define NSTEP 128            // 127 real increments + 1 zero pad (identity step)
#define OUT_PER_B 22620      // 12 + 144 + 1728 + 20736
#define BLOCK 896            // 14 waves; 864 active = 6*12*12

__global__ __launch_bounds__(BLOCK)
void sig_kernel(const float* __restrict__ path, float* __restrict__ out) {
    const int bid = blockIdx.x;
    const int b  = bid >> 1;          // batch
    const int ih = bid & 1;           // which i-half this block owns
    const int t  = threadIdx.x;

    __shared__ __align__(16) float P[NPTS * NC];       // 6144 B
    __shared__ __align__(16) float Drow[NSTEP * NC];   // 6144 B, row-major incs
    __shared__ __align__(16) float DT[NC * NSTEP];     // 6144 B, transposed incs

    // ---- stage path, build increment tables (both layouts) ----
    const float* pb = path + (size_t)b * (NPTS * NC);
    for (int idx = t; idx < NPTS * NC; idx += BLOCK) P[idx] = pb[idx];
    __syncthreads();
    for (int idx = t; idx < NSTEP * NC; idx += BLOCK) {
        int s = idx / NC;
        int c = idx - s * NC;
        float d = (s < NPTS - 1) ? (P[idx + NC] - P[idx]) : 0.f; // pad step = 0
        Drow[idx] = d;
        DT[c * NSTEP + s] = d;
    }
    __syncthreads();

    if (t < 864) {
        const int il = t / 144;            // 0..5
        const int rem = t - il * 144;
        const int j = rem / 12;            // 0..11
        const int k = rem - j * 12;        // 0..11
        const int i = ih * 6 + il;         // global leading index

        float acc[12];
        #pragma unroll
        for (int l = 0; l < 12; ++l) acc[l] = 0.f;
        float s3 = 0.f, s2 = 0.f, s1 = 0.f;

        const float4* drow = (const float4*)Drow;            // 3 float4 per step
        const float4* dti  = (const float4*)&DT[i * NSTEP];
        const float4* dtj  = (const float4*)&DT[j * NSTEP];
        const float4* dtk  = (const float4*)&DT[k * NSTEP];

        for (int sq = 0; sq < NSTEP / 4; ++sq) {
            float4 di4 = dti[sq];
            float4 dj4 = dtj[sq];
            float4 dk4 = dtk[sq];
            #pragma unroll
            for (int u = 0; u < 4; ++u) {
                const int s = sq * 4 + u;
                float4 da = drow[s * 3 + 0];
                float4 db = drow[s * 3 + 1];
                float4 dc = drow[s * 3 + 2];
                float di = (&di4.x)[u];
                float dj = (&dj4.x)[u];
                float dk = (&dk4.x)[u];

                // Horner-factored Chen step (uses OLD s1,s2,s3)
                float A4 = (s1 + 0.25f * di) * (1.f / 3.f);
                float B4 = (s2 + dj * A4) * 0.5f;
                float C3 = s3 + dk * B4;

                acc[0]  += C3 * da.x;  acc[1]  += C3 * da.y;
                acc[2]  += C3 * da.z;  acc[3]  += C3 * da.w;
                acc[4]  += C3 * db.x;  acc[5]  += C3 * db.y;
                acc[6]  += C3 * db.z;  acc[7]  += C3 * db.w;
                acc[8]  += C3 * dc.x;  acc[9]  += C3 * dc.y;
                acc[10] += C3 * dc.z;  acc[11] += C3 * dc.w;

                float A3 = (s1 + di * (1.f / 3.f)) * 0.5f;
                float C2 = s2 + dj * A3;
                s3 += dk * C2;
                s2 += dj * (s1 + 0.5f * di);
                s1 += di;
            }
        }

        // ---- epilogue: layout [lvl1 | lvl2 | lvl3 | lvl4], partitioned by i ----
        float* ob = out + (size_t)b * OUT_PER_B;
        if (j == 0 && k == 0) ob[i] = s1;                     // level 1
        if (k == 0) ob[12 + i * 12 + j] = s2;                 // level 2
        ob[156 + (i * 12 + j) * 12 + k] = s3;                 // level 3
        float* o4 = ob + 1884 + (size_t)((i * 12 + j) * 12 + k) * 12;  // level 4
        float4* o4v = (float4*)o4;                            // 48B, 16B-aligned
        o4v[0] = make_float4(acc[0], acc[1], acc[2],  acc[3]);
        o4v[1] = make_float4(acc[4], acc[5], acc[6],  acc[7]);
        o4v[2] = make_float4(acc[8], acc[9], acc[10], acc[11]);
    }
}

extern "C" void kernel_launch(void* const* d_in, const int* in_sizes, int n_in,
                              void* d_out, int out_size, void* d_ws, size_t ws_size,
                              hipStream_t stream) {
    const float* path = (const float*)d_in[0];
    float* out = (float*)d_out;
    int nbatch = in_sizes[0] / (NPTS * NC);   // = 128
    sig_kernel<<<nbatch * 2, BLOCK, 0, stream>>>(path, out);
}